// Round 2
// baseline (725.875 us; speedup 1.0000x reference)
//
#include <hip/hip_runtime.h>
#include <stdint.h>
#include <math.h>

#define NN 8192
#define DD 512
#define KSEL 4096
#define NW 128  // 64-bit words per row bitset (8192 bits)

// ---------------- Kernel 1: w64 = h @ W + b (f64), val = sigmoid(w64) ------
__global__ __launch_bounds__(256) void k_scores(const float* __restrict__ h,
                                                const float* __restrict__ W,
                                                const float* __restrict__ b,
                                                double* __restrict__ w64,
                                                float* __restrict__ val) {
    int wave = threadIdx.x >> 6;
    int lane = threadIdx.x & 63;
    int row  = blockIdx.x * 4 + wave;
    const float4* h4 = (const float4*)(h + (size_t)row * DD);
    const float4* w4 = (const float4*)W;
    float4 a0 = h4[lane * 2], a1 = h4[lane * 2 + 1];
    float4 b0 = w4[lane * 2], b1 = w4[lane * 2 + 1];
    double p = (double)a0.x * (double)b0.x + (double)a0.y * (double)b0.y
             + (double)a0.z * (double)b0.z + (double)a0.w * (double)b0.w
             + (double)a1.x * (double)b1.x + (double)a1.y * (double)b1.y
             + (double)a1.z * (double)b1.z + (double)a1.w * (double)b1.w;
    #pragma unroll
    for (int off = 32; off >= 1; off >>= 1) p += __shfl_xor(p, off);
    if (lane == 0) {
        double wgt = p + (double)b[0];
        w64[row] = wgt;
        val[row] = (float)(1.0 / (1.0 + exp(-wgt)));
    }
}

// ---------------- Kernel 2: top-K by stable rank on f64 keys ----------------
// rank_i = #{j: w_j > w_i} + #{j < i: w_j == w_i}  (== jax.lax.top_k order;
// sigmoid is monotone so score order == weight order)
__global__ __launch_bounds__(256) void k_topk(const double* __restrict__ w64,
                                              int* __restrict__ idx_i,
                                              float* __restrict__ idx_f) {
    __shared__ double s[2048];
    int i = blockIdx.x * 256 + threadIdx.x;
    double wi = w64[i];
    int rank = 0;
    for (int c = 0; c < 4; ++c) {
        __syncthreads();
        for (int t = threadIdx.x; t < 2048; t += 256) s[t] = w64[c * 2048 + t];
        __syncthreads();
        int base = c * 2048;
        for (int j = 0; j < 2048; ++j) {
            double wj = s[j];
            rank += (wj > wi) || (wj == wi && (base + j) < i);
        }
    }
    if (rank < KSEL) {
        idx_i[rank] = i;
        idx_f[rank] = (float)i;
    }
}

// ---------------- Kernel 3: pack g rows into bitsets ----------------
__global__ __launch_bounds__(256) void k_pack(const float* __restrict__ g,
                                              uint64_t* __restrict__ R) {
    int wave = threadIdx.x >> 6;
    int lane = threadIdx.x & 63;
    int row  = blockIdx.x * 4 + wave;
    const float* gr = g + (size_t)row * NN;
    uint64_t* Rr = R + (size_t)row * NW;
    for (int w = 0; w < NW; ++w) {
        float v = gr[w * 64 + lane];
        uint64_t m = __ballot(v != 0.0f);
        if (lane == 0) Rr[w] = m;
    }
}

// ---------------- Kernel 4: new_h = h[idx] * values ----------------
__global__ __launch_bounds__(128) void k_newh(const float* __restrict__ h,
                                              const float* __restrict__ val,
                                              const int* __restrict__ idx_i,
                                              float* __restrict__ out_h) {
    int r = blockIdx.x;
    int i = idx_i[r];
    float v = val[i];
    const float4* src = (const float4*)(h + (size_t)i * DD);
    float4* dst = (float4*)(out_h + (size_t)r * DD);
    float4 x = src[threadIdx.x];
    x.x *= v; x.y *= v; x.z *= v; x.w *= v;
    dst[threadIdx.x] = x;
}

// ---------------- Kernel 5: new_g rows via bitset OR of neighbor rows ----
__global__ __launch_bounds__(256) void k_newg(const uint64_t* __restrict__ R,
                                              const int* __restrict__ idx_i,
                                              float* __restrict__ out_g) {
    __shared__ int idx_s[KSEL];
    __shared__ uint64_t T[4][NW];
    for (int t = threadIdx.x; t < KSEL; t += 256) idx_s[t] = idx_i[t];
    __syncthreads();

    int wave = threadIdx.x >> 6;
    int lane = threadIdx.x & 63;
    int r = blockIdx.x * 4 + wave;
    int i = idx_s[r];

    // phase 1: OR of neighbor bitsets; lane holds words 2*lane, 2*lane+1
    const uint64_t* Ri = R + (size_t)i * NW;
    uint64_t acc0 = 0, acc1 = 0;
    for (int w = 0; w < NW; ++w) {
        uint64_t m = Ri[w];  // wave-uniform load (broadcast)
        while (m) {
            int k = (w << 6) + __builtin_ctzll(m);
            m &= m - 1;
            const uint64_t* Rk = R + (size_t)k * NW + lane * 2;
            acc0 |= Rk[0];
            acc1 |= Rk[1];
        }
    }
    T[wave][lane * 2]     = acc0;
    T[wave][lane * 2 + 1] = acc1;
    __syncthreads();

    // phase 2: gather bits at selected columns, popcount for row sum
    const uint64_t* Tw = T[wave];
    uint64_t bits = 0;
    #pragma unroll
    for (int it = 0; it < 16; ++it) {
        int4 j4 = *(const int4*)&idx_s[it * 256 + lane * 4];
        uint64_t b0 = (Tw[j4.x >> 6] >> (j4.x & 63)) & 1ull;
        uint64_t b1 = (Tw[j4.y >> 6] >> (j4.y & 63)) & 1ull;
        uint64_t b2 = (Tw[j4.z >> 6] >> (j4.z & 63)) & 1ull;
        uint64_t b3 = (Tw[j4.w >> 6] >> (j4.w & 63)) & 1ull;
        bits |= (b0 << (it * 4)) | (b1 << (it * 4 + 1))
              | (b2 << (it * 4 + 2)) | (b3 << (it * 4 + 3));
    }
    int cnt = __popcll(bits);
    #pragma unroll
    for (int off = 32; off >= 1; off >>= 1) cnt += __shfl_xor(cnt, off);
    float recip = 1.0f / (float)cnt;  // bit * recip == exact 1/rowsum

    float4* dst = (float4*)(out_g + (size_t)r * KSEL);
    #pragma unroll
    for (int it = 0; it < 16; ++it) {
        float4 v;
        v.x = ((bits >> (it * 4 + 0)) & 1ull) ? recip : 0.0f;
        v.y = ((bits >> (it * 4 + 1)) & 1ull) ? recip : 0.0f;
        v.z = ((bits >> (it * 4 + 2)) & 1ull) ? recip : 0.0f;
        v.w = ((bits >> (it * 4 + 3)) & 1ull) ? recip : 0.0f;
        dst[it * 64 + lane] = v;
    }
}

extern "C" void kernel_launch(void* const* d_in, const int* in_sizes, int n_in,
                              void* d_out, int out_size, void* d_ws, size_t ws_size,
                              hipStream_t stream) {
    const float* g = (const float*)d_in[0];
    const float* h = (const float*)d_in[1];
    const float* W = (const float*)d_in[2];
    const float* b = (const float*)d_in[3];

    float* out_g   = (float*)d_out;                                   // K*K
    float* out_h   = out_g + (size_t)KSEL * KSEL;                     // K*D
    float* out_idx = out_h + (size_t)KSEL * DD;                       // K

    char* ws = (char*)d_ws;
    double*   w64    = (double*)ws;                      // 64 KB
    float*    val    = (float*)(ws + 65536);             // 32 KB
    int*      idx_i  = (int*)(ws + 98304);               // 16 KB
    uint64_t* R      = (uint64_t*)(ws + 131072);         // 8 MB

    k_scores<<<NN / 4, 256, 0, stream>>>(h, W, b, w64, val);
    k_pack<<<NN / 4, 256, 0, stream>>>(g, R);
    k_topk<<<NN / 256, 256, 0, stream>>>(w64, idx_i, out_idx);
    k_newh<<<KSEL, 128, 0, stream>>>(h, val, idx_i, out_h);
    k_newg<<<KSEL / 4, 256, 0, stream>>>(R, idx_i, out_g);
}

// Round 3
// 181.901 us; speedup vs baseline: 3.9905x; 3.9905x over previous
//
#include <hip/hip_runtime.h>
#include <stdint.h>
#include <math.h>

#define NN 8192
#define DD 512
#define KSEL 4096
#define NW 128  // 64-bit words per row bitset (8192 bits)

// ---------------- Kernel 1: w64 = h @ W + b (f64), val = sigmoid(w64) ------
__global__ __launch_bounds__(256) void k_scores(const float* __restrict__ h,
                                                const float* __restrict__ W,
                                                const float* __restrict__ b,
                                                double* __restrict__ w64,
                                                float* __restrict__ val) {
    int wave = threadIdx.x >> 6;
    int lane = threadIdx.x & 63;
    int row  = blockIdx.x * 4 + wave;
    const float4* h4 = (const float4*)(h + (size_t)row * DD);
    const float4* w4 = (const float4*)W;
    float4 a0 = h4[lane * 2], a1 = h4[lane * 2 + 1];
    float4 b0 = w4[lane * 2], b1 = w4[lane * 2 + 1];
    double p = (double)a0.x * (double)b0.x + (double)a0.y * (double)b0.y
             + (double)a0.z * (double)b0.z + (double)a0.w * (double)b0.w
             + (double)a1.x * (double)b1.x + (double)a1.y * (double)b1.y
             + (double)a1.z * (double)b1.z + (double)a1.w * (double)b1.w;
    #pragma unroll
    for (int off = 32; off >= 1; off >>= 1) p += __shfl_xor(p, off);
    if (lane == 0) {
        double wgt = p + (double)b[0];
        w64[row] = wgt;
        val[row] = (float)(1.0 / (1.0 + exp(-wgt)));
    }
}

// ---------------- Kernel 2: top-K by stable rank on f64 keys ----------------
// rank_i = #{j: w_j > w_i} + #{j < i: w_j == w_i}  (== jax.lax.top_k order;
// sigmoid is monotone so score order == weight order)
// One wave per row i; 64 lanes stride over j; 16 rows per 1024-thread block.
__global__ __launch_bounds__(1024) void k_topk(const double* __restrict__ w64,
                                               int* __restrict__ idx_i,
                                               float* __restrict__ idx_f) {
    __shared__ double s[NN];  // 64 KB
    for (int t = threadIdx.x; t < NN; t += 1024) s[t] = w64[t];
    __syncthreads();

    int wave = threadIdx.x >> 6;          // 0..15
    int lane = threadIdx.x & 63;
    int i = blockIdx.x * 16 + wave;
    double wi = s[i];
    int rank = 0;
    #pragma unroll 4
    for (int j = lane; j < NN; j += 64) {
        double wj = s[j];
        rank += (wj > wi) || (wj == wi && j < i);
    }
    #pragma unroll
    for (int off = 32; off >= 1; off >>= 1) rank += __shfl_xor(rank, off);
    if (lane == 0 && rank < KSEL) {
        idx_i[rank] = i;
        idx_f[rank] = (float)i;
    }
}

// ---------------- Kernel 3: pack g rows into bitsets ----------------
__global__ __launch_bounds__(256) void k_pack(const float* __restrict__ g,
                                              uint64_t* __restrict__ R) {
    int wave = threadIdx.x >> 6;
    int lane = threadIdx.x & 63;
    int row  = blockIdx.x * 4 + wave;
    const float* gr = g + (size_t)row * NN;
    uint64_t* Rr = R + (size_t)row * NW;
    for (int w = 0; w < NW; ++w) {
        float v = gr[w * 64 + lane];
        uint64_t m = __ballot(v != 0.0f);
        if (lane == 0) Rr[w] = m;
    }
}

// ---------------- Kernel 4: new_h = h[idx] * values ----------------
__global__ __launch_bounds__(128) void k_newh(const float* __restrict__ h,
                                              const float* __restrict__ val,
                                              const int* __restrict__ idx_i,
                                              float* __restrict__ out_h) {
    int r = blockIdx.x;
    int i = idx_i[r];
    float v = val[i];
    const float4* src = (const float4*)(h + (size_t)i * DD);
    float4* dst = (float4*)(out_h + (size_t)r * DD);
    float4 x = src[threadIdx.x];
    x.x *= v; x.y *= v; x.z *= v; x.w *= v;
    dst[threadIdx.x] = x;
}

// ---------------- Kernel 5: new_g rows via bitset OR of neighbor rows ----
__global__ __launch_bounds__(256) void k_newg(const uint64_t* __restrict__ R,
                                              const int* __restrict__ idx_i,
                                              float* __restrict__ out_g) {
    __shared__ int idx_s[KSEL];
    __shared__ uint64_t T[4][NW];
    for (int t = threadIdx.x; t < KSEL; t += 256) idx_s[t] = idx_i[t];
    __syncthreads();

    int wave = threadIdx.x >> 6;
    int lane = threadIdx.x & 63;
    int r = blockIdx.x * 4 + wave;
    int i = idx_s[r];

    // phase 1: OR of neighbor bitsets; lane holds words 2*lane, 2*lane+1
    const uint64_t* Ri = R + (size_t)i * NW;
    uint64_t acc0 = 0, acc1 = 0;
    for (int w = 0; w < NW; ++w) {
        uint64_t m = Ri[w];  // wave-uniform load (broadcast)
        while (m) {
            int k = (w << 6) + __builtin_ctzll(m);
            m &= m - 1;
            const uint64_t* Rk = R + (size_t)k * NW + lane * 2;
            acc0 |= Rk[0];
            acc1 |= Rk[1];
        }
    }
    T[wave][lane * 2]     = acc0;
    T[wave][lane * 2 + 1] = acc1;
    __syncthreads();

    // phase 2: gather bits at selected columns, popcount for row sum
    const uint64_t* Tw = T[wave];
    uint64_t bits = 0;
    #pragma unroll
    for (int it = 0; it < 16; ++it) {
        int4 j4 = *(const int4*)&idx_s[it * 256 + lane * 4];
        uint64_t b0 = (Tw[j4.x >> 6] >> (j4.x & 63)) & 1ull;
        uint64_t b1 = (Tw[j4.y >> 6] >> (j4.y & 63)) & 1ull;
        uint64_t b2 = (Tw[j4.z >> 6] >> (j4.z & 63)) & 1ull;
        uint64_t b3 = (Tw[j4.w >> 6] >> (j4.w & 63)) & 1ull;
        bits |= (b0 << (it * 4)) | (b1 << (it * 4 + 1))
              | (b2 << (it * 4 + 2)) | (b3 << (it * 4 + 3));
    }
    int cnt = __popcll(bits);
    #pragma unroll
    for (int off = 32; off >= 1; off >>= 1) cnt += __shfl_xor(cnt, off);
    float recip = 1.0f / (float)cnt;  // bit * recip == exact 1/rowsum

    float4* dst = (float4*)(out_g + (size_t)r * KSEL);
    #pragma unroll
    for (int it = 0; it < 16; ++it) {
        float4 v;
        v.x = ((bits >> (it * 4 + 0)) & 1ull) ? recip : 0.0f;
        v.y = ((bits >> (it * 4 + 1)) & 1ull) ? recip : 0.0f;
        v.z = ((bits >> (it * 4 + 2)) & 1ull) ? recip : 0.0f;
        v.w = ((bits >> (it * 4 + 3)) & 1ull) ? recip : 0.0f;
        dst[it * 64 + lane] = v;
    }
}

extern "C" void kernel_launch(void* const* d_in, const int* in_sizes, int n_in,
                              void* d_out, int out_size, void* d_ws, size_t ws_size,
                              hipStream_t stream) {
    const float* g = (const float*)d_in[0];
    const float* h = (const float*)d_in[1];
    const float* W = (const float*)d_in[2];
    const float* b = (const float*)d_in[3];

    float* out_g   = (float*)d_out;                                   // K*K
    float* out_h   = out_g + (size_t)KSEL * KSEL;                     // K*D
    float* out_idx = out_h + (size_t)KSEL * DD;                       // K

    char* ws = (char*)d_ws;
    double*   w64    = (double*)ws;                      // 64 KB
    float*    val    = (float*)(ws + 65536);             // 32 KB
    int*      idx_i  = (int*)(ws + 98304);               // 16 KB
    uint64_t* R      = (uint64_t*)(ws + 131072);         // 8 MB

    k_scores<<<NN / 4, 256, 0, stream>>>(h, W, b, w64, val);
    k_pack<<<NN / 4, 256, 0, stream>>>(g, R);
    k_topk<<<NN / 16, 1024, 0, stream>>>(w64, idx_i, out_idx);
    k_newh<<<KSEL, 128, 0, stream>>>(h, val, idx_i, out_h);
    k_newg<<<KSEL / 4, 256, 0, stream>>>(R, idx_i, out_g);
}

// Round 4
// 136.317 us; speedup vs baseline: 5.3249x; 1.3344x over previous
//
#include <hip/hip_runtime.h>
#include <stdint.h>
#include <math.h>

#define NN 8192
#define DD 512
#define KSEL 4096
#define NW 128  // 64-bit words per row bitset (8192 bits)

// Bit permutation pi (internal to R/T bitsets):
//   column c = g*256 + l*4 + e  (g=c>>8, l=(c>>2)&63, e=c&3)
//   stored at word g*4 + e, bit l.
// k_pack produces this layout for free via 4 ballots of a per-lane nibble;
// k_newg decodes/encodes with the same mapping everywhere.

// ---------------- Kernel 1: w64 = h @ W + b (f64), val = sigmoid(w64) ------
__global__ __launch_bounds__(256) void k_scores(const float* __restrict__ h,
                                                const float* __restrict__ W,
                                                const float* __restrict__ b,
                                                double* __restrict__ w64,
                                                float* __restrict__ val) {
    int wave = threadIdx.x >> 6;
    int lane = threadIdx.x & 63;
    int row  = blockIdx.x * 4 + wave;
    const float4* h4 = (const float4*)(h + (size_t)row * DD);
    const float4* w4 = (const float4*)W;
    float4 a0 = h4[lane * 2], a1 = h4[lane * 2 + 1];
    float4 b0 = w4[lane * 2], b1 = w4[lane * 2 + 1];
    double p = (double)a0.x * (double)b0.x + (double)a0.y * (double)b0.y
             + (double)a0.z * (double)b0.z + (double)a0.w * (double)b0.w
             + (double)a1.x * (double)b1.x + (double)a1.y * (double)b1.y
             + (double)a1.z * (double)b1.z + (double)a1.w * (double)b1.w;
    #pragma unroll
    for (int off = 32; off >= 1; off >>= 1) p += __shfl_xor(p, off);
    if (lane == 0) {
        double wgt = p + (double)b[0];
        w64[row] = wgt;
        val[row] = (float)(1.0 / (1.0 + exp(-wgt)));
    }
}

// ---------------- Kernel 2: top-K by stable rank on f64 keys ----------------
__global__ __launch_bounds__(1024) void k_topk(const double* __restrict__ w64,
                                               int* __restrict__ idx_i,
                                               float* __restrict__ idx_f) {
    __shared__ double s[NN];  // 64 KB
    for (int t = threadIdx.x; t < NN; t += 1024) s[t] = w64[t];
    __syncthreads();

    int wave = threadIdx.x >> 6;          // 0..15
    int lane = threadIdx.x & 63;
    int i = blockIdx.x * 16 + wave;
    double wi = s[i];
    int rank = 0;
    #pragma unroll 4
    for (int j = lane; j < NN; j += 64) {
        double wj = s[j];
        rank += (wj > wi) || (wj == wi && j < i);
    }
    #pragma unroll
    for (int off = 32; off >= 1; off >>= 1) rank += __shfl_xor(rank, off);
    if (lane == 0 && rank < KSEL) {
        idx_i[rank] = i;
        idx_f[rank] = (float)i;
    }
}

// ---------------- Kernel 3: pack g rows into pi-permuted bitsets ------------
__global__ __launch_bounds__(256) void k_pack(const float* __restrict__ g,
                                              uint64_t* __restrict__ R) {
    int wave = threadIdx.x >> 6;
    int lane = threadIdx.x & 63;
    int row  = blockIdx.x * 4 + wave;
    const float4* gr = (const float4*)(g + (size_t)row * NN);
    uint64_t* Rr = R + (size_t)row * NW;
    #pragma unroll 4
    for (int gi = 0; gi < 32; ++gi) {
        float4 v = gr[gi * 64 + lane];  // 1 KB per wave-instruction
        int n = (v.x != 0.0f) | ((v.y != 0.0f) << 1)
              | ((v.z != 0.0f) << 2) | ((v.w != 0.0f) << 3);
        uint64_t b0 = __ballot(n & 1);
        uint64_t b1 = __ballot(n & 2);
        uint64_t b2 = __ballot(n & 4);
        uint64_t b3 = __ballot(n & 8);
        if (lane == 0) {
            Rr[gi * 4 + 0] = b0;
            Rr[gi * 4 + 1] = b1;
            Rr[gi * 4 + 2] = b2;
            Rr[gi * 4 + 3] = b3;
        }
    }
}

// ---------------- Kernel 4: new_h = h[idx] * values ----------------
__global__ __launch_bounds__(128) void k_newh(const float* __restrict__ h,
                                              const float* __restrict__ val,
                                              const int* __restrict__ idx_i,
                                              float* __restrict__ out_h) {
    int r = blockIdx.x;
    int i = idx_i[r];
    float v = val[i];
    const float4* src = (const float4*)(h + (size_t)i * DD);
    float4* dst = (float4*)(out_h + (size_t)r * DD);
    float4 x = src[threadIdx.x];
    x.x *= v; x.y *= v; x.z *= v; x.w *= v;
    dst[threadIdx.x] = x;
}

// ---------------- Kernel 5: new_g rows via bitset OR of neighbor rows ----
__global__ __launch_bounds__(256) void k_newg(const uint64_t* __restrict__ R,
                                              const int* __restrict__ idx_i,
                                              float* __restrict__ out_g) {
    __shared__ int idx_s[KSEL];        // 16 KB
    __shared__ uint64_t T[4][NW];      // 4 KB
    __shared__ uint64_t Rl[4][NW];     // 4 KB — this wave's own row bitset
    for (int t = threadIdx.x; t < KSEL; t += 256) idx_s[t] = idx_i[t];
    __syncthreads();

    int wave = threadIdx.x >> 6;
    int lane = threadIdx.x & 63;
    int r = blockIdx.x * 4 + wave;
    int i = idx_s[r];

    // stage Ri into LDS with ONE coalesced load (kills 128 serial uniform
    // global loads + their per-iteration vmcnt stalls)
    const uint64_t* Ri = R + (size_t)i * NW;
    *(ulonglong2*)&Rl[wave][lane * 2] = *(const ulonglong2*)&Ri[lane * 2];

    // phase 1: OR of neighbor bitsets; lane holds words 2*lane, 2*lane+1
    uint64_t acc0 = 0, acc1 = 0;
    for (int w = 0; w < NW; ++w) {
        uint64_t m = Rl[wave][w];  // LDS broadcast read
        while (m) {
            int l = __builtin_ctzll(m);
            m &= m - 1;
            // pi-decode: word w = g*4+e, bit l -> neighbor k = g*256 + l*4 + e
            int k = ((w >> 2) << 8) + (l << 2) + (w & 3);
            const uint64_t* Rk = R + (size_t)k * NW + lane * 2;
            acc0 |= Rk[0];
            acc1 |= Rk[1];
        }
    }
    T[wave][lane * 2]     = acc0;
    T[wave][lane * 2 + 1] = acc1;
    __syncthreads();

    // phase 2: gather bits at selected columns (pi-encoded), popcount row sum
    const uint64_t* Tw = T[wave];
    uint64_t bits = 0;
    #pragma unroll
    for (int it = 0; it < 16; ++it) {
        int4 j4 = *(const int4*)&idx_s[it * 256 + lane * 4];
        // column c -> word ((c>>8)<<2)|(c&3), bit (c>>2)&63
        uint64_t b0 = (Tw[((j4.x >> 8) << 2) | (j4.x & 3)] >> ((j4.x >> 2) & 63)) & 1ull;
        uint64_t b1 = (Tw[((j4.y >> 8) << 2) | (j4.y & 3)] >> ((j4.y >> 2) & 63)) & 1ull;
        uint64_t b2 = (Tw[((j4.z >> 8) << 2) | (j4.z & 3)] >> ((j4.z >> 2) & 63)) & 1ull;
        uint64_t b3 = (Tw[((j4.w >> 8) << 2) | (j4.w & 3)] >> ((j4.w >> 2) & 63)) & 1ull;
        bits |= (b0 << (it * 4)) | (b1 << (it * 4 + 1))
              | (b2 << (it * 4 + 2)) | (b3 << (it * 4 + 3));
    }
    int cnt = __popcll(bits);
    #pragma unroll
    for (int off = 32; off >= 1; off >>= 1) cnt += __shfl_xor(cnt, off);
    float recip = 1.0f / (float)cnt;  // bit * recip == exact 1/rowsum

    float4* dst = (float4*)(out_g + (size_t)r * KSEL);
    #pragma unroll
    for (int it = 0; it < 16; ++it) {
        float4 v;
        v.x = ((bits >> (it * 4 + 0)) & 1ull) ? recip : 0.0f;
        v.y = ((bits >> (it * 4 + 1)) & 1ull) ? recip : 0.0f;
        v.z = ((bits >> (it * 4 + 2)) & 1ull) ? recip : 0.0f;
        v.w = ((bits >> (it * 4 + 3)) & 1ull) ? recip : 0.0f;
        dst[it * 64 + lane] = v;
    }
}

extern "C" void kernel_launch(void* const* d_in, const int* in_sizes, int n_in,
                              void* d_out, int out_size, void* d_ws, size_t ws_size,
                              hipStream_t stream) {
    const float* g = (const float*)d_in[0];
    const float* h = (const float*)d_in[1];
    const float* W = (const float*)d_in[2];
    const float* b = (const float*)d_in[3];

    float* out_g   = (float*)d_out;                                   // K*K
    float* out_h   = out_g + (size_t)KSEL * KSEL;                     // K*D
    float* out_idx = out_h + (size_t)KSEL * DD;                       // K

    char* ws = (char*)d_ws;
    double*   w64    = (double*)ws;                      // 64 KB
    float*    val    = (float*)(ws + 65536);             // 32 KB
    int*      idx_i  = (int*)(ws + 98304);               // 16 KB
    uint64_t* R      = (uint64_t*)(ws + 131072);         // 8 MB

    k_scores<<<NN / 4, 256, 0, stream>>>(h, W, b, w64, val);
    k_pack<<<NN / 4, 256, 0, stream>>>(g, R);
    k_topk<<<NN / 16, 1024, 0, stream>>>(w64, idx_i, out_idx);
    k_newh<<<KSEL, 128, 0, stream>>>(h, val, idx_i, out_h);
    k_newg<<<KSEL / 4, 256, 0, stream>>>(R, idx_i, out_g);
}

// Round 5
// 124.454 us; speedup vs baseline: 5.8325x; 1.0953x over previous
//
#include <hip/hip_runtime.h>
#include <stdint.h>
#include <math.h>

#define NN 8192
#define DD 512
#define KSEL 4096
#define NW 128  // 64-bit words per row bitset (8192 bits)

// Bit permutation pi (internal to R/T bitsets):
//   column c = g*256 + l*4 + e  (g=c>>8, l=(c>>2)&63, e=c&3)
//   stored at word g*4 + e, bit l.

// ---------------- Kernel 1: w64 = h @ W + b (f64), val = sigmoid(w64) ------
__global__ __launch_bounds__(256) void k_scores(const float* __restrict__ h,
                                                const float* __restrict__ W,
                                                const float* __restrict__ b,
                                                double* __restrict__ w64,
                                                float* __restrict__ val) {
    int wave = threadIdx.x >> 6;
    int lane = threadIdx.x & 63;
    int row  = blockIdx.x * 4 + wave;
    const float4* h4 = (const float4*)(h + (size_t)row * DD);
    const float4* w4 = (const float4*)W;
    float4 a0 = h4[lane * 2], a1 = h4[lane * 2 + 1];
    float4 b0 = w4[lane * 2], b1 = w4[lane * 2 + 1];
    double p = (double)a0.x * (double)b0.x + (double)a0.y * (double)b0.y
             + (double)a0.z * (double)b0.z + (double)a0.w * (double)b0.w
             + (double)a1.x * (double)b1.x + (double)a1.y * (double)b1.y
             + (double)a1.z * (double)b1.z + (double)a1.w * (double)b1.w;
    #pragma unroll
    for (int off = 32; off >= 1; off >>= 1) p += __shfl_xor(p, off);
    if (lane == 0) {
        double wgt = p + (double)b[0];
        w64[row] = wgt;
        val[row] = (float)(1.0 / (1.0 + exp(-wgt)));
    }
}

// ---------------- Kernel 2: top-K by stable rank on f64 keys ----------------
__global__ __launch_bounds__(1024) void k_topk(const double* __restrict__ w64,
                                               int* __restrict__ idx_i,
                                               float* __restrict__ idx_f) {
    __shared__ double s[NN];  // 64 KB
    for (int t = threadIdx.x; t < NN; t += 1024) s[t] = w64[t];
    __syncthreads();

    int wave = threadIdx.x >> 6;          // 0..15
    int lane = threadIdx.x & 63;
    int i = blockIdx.x * 16 + wave;
    double wi = s[i];
    int rank = 0;
    #pragma unroll 4
    for (int j = lane; j < NN; j += 64) {
        double wj = s[j];
        rank += (wj > wi) || (wj == wi && j < i);
    }
    #pragma unroll
    for (int off = 32; off >= 1; off >>= 1) rank += __shfl_xor(rank, off);
    if (lane == 0 && rank < KSEL) {
        idx_i[rank] = i;
        idx_f[rank] = (float)i;
    }
}

// ---------------- Kernel 3: pack g rows into pi-permuted bitsets ------------
__global__ __launch_bounds__(256) void k_pack(const float* __restrict__ g,
                                              uint64_t* __restrict__ R) {
    int wave = threadIdx.x >> 6;
    int lane = threadIdx.x & 63;
    int row  = blockIdx.x * 4 + wave;
    const float4* gr = (const float4*)(g + (size_t)row * NN);
    uint64_t* Rr = R + (size_t)row * NW;
    #pragma unroll 4
    for (int gi = 0; gi < 32; ++gi) {
        float4 v = gr[gi * 64 + lane];  // 1 KB per wave-instruction
        int n = (v.x != 0.0f) | ((v.y != 0.0f) << 1)
              | ((v.z != 0.0f) << 2) | ((v.w != 0.0f) << 3);
        uint64_t b0 = __ballot(n & 1);
        uint64_t b1 = __ballot(n & 2);
        uint64_t b2 = __ballot(n & 4);
        uint64_t b3 = __ballot(n & 8);
        if (lane == 0) {
            Rr[gi * 4 + 0] = b0;
            Rr[gi * 4 + 1] = b1;
            Rr[gi * 4 + 2] = b2;
            Rr[gi * 4 + 3] = b3;
        }
    }
}

// ---------------- Kernel 4: new_h = h[idx] * values ----------------
__global__ __launch_bounds__(128) void k_newh(const float* __restrict__ h,
                                              const float* __restrict__ val,
                                              const int* __restrict__ idx_i,
                                              float* __restrict__ out_h) {
    int r = blockIdx.x;
    int i = idx_i[r];
    float v = val[i];
    const float4* src = (const float4*)(h + (size_t)i * DD);
    float4* dst = (float4*)(out_h + (size_t)r * DD);
    float4 x = src[threadIdx.x];
    x.x *= v; x.y *= v; x.z *= v; x.w *= v;
    dst[threadIdx.x] = x;
}

// ---------------- Kernel 5: new_g rows via bitset OR of neighbor rows ----
__global__ __launch_bounds__(256) void k_newg(const uint64_t* __restrict__ R,
                                              const int* __restrict__ idx_i,
                                              float* __restrict__ out_g) {
    __shared__ int idx_s[KSEL];                        // 16 KB
    __shared__ uint64_t T[4][NW];                      // 4 KB
    __shared__ __align__(16) uint16_t nbr[4][528];     // ~4 KB neighbor lists
    for (int t = threadIdx.x; t < KSEL; t += 256) idx_s[t] = idx_i[t];
    __syncthreads();

    int wave = threadIdx.x >> 6;
    int lane = threadIdx.x & 63;
    int r = blockIdx.x * 4 + wave;
    int i = idx_s[r];

    // --- extract neighbor list of row i into LDS (registers -> prefix -> scatter)
    // lane holds own-row words w0=2*lane, w1=2*lane+1 (one coalesced 16B load)
    ulonglong2 own = *((const ulonglong2*)(R + (size_t)i * NW) + lane);
    uint64_t m0 = own.x, m1 = own.y;
    int mycnt = __popcll(m0) + __popcll(m1);
    int incl = mycnt;
    #pragma unroll
    for (int d = 1; d < 64; d <<= 1) {
        int v = __shfl_up(incl, d);
        if (lane >= d) incl += v;
    }
    int pos = incl - mycnt;                 // exclusive prefix
    int total = __shfl(incl, 63);
    int w0 = lane * 2, w1 = lane * 2 + 1;
    while (m0) {
        int l = __builtin_ctzll(m0); m0 &= m0 - 1;
        nbr[wave][pos++] = (uint16_t)(((w0 >> 2) << 8) + (l << 2) + (w0 & 3));
    }
    while (m1) {
        int l = __builtin_ctzll(m1); m1 &= m1 - 1;
        nbr[wave][pos++] = (uint16_t)(((w1 >> 2) << 8) + (l << 2) + (w1 & 3));
    }
    // pad list to multiple of 8 with entry 0 (OR is idempotent)
    int totalPad = (total + 7) & ~7;
    if (lane < totalPad - total) nbr[wave][total + lane] = nbr[wave][0];

    // --- phase 1: OR neighbor bitsets, 8 independent 16B loads in flight
    const ulonglong2* R2 = (const ulonglong2*)R;  // 64 ulonglong2 per row
    uint64_t acc0 = 0, acc1 = 0;
    const uint16_t* nb = nbr[wave];
    for (int n = 0; n < totalPad; n += 8) {
        uint4 pk = *(const uint4*)&nb[n];   // 8 neighbor ids, broadcast LDS read
        int k0 = pk.x & 0xffff, k1 = pk.x >> 16;
        int k2 = pk.y & 0xffff, k3 = pk.y >> 16;
        int k4 = pk.z & 0xffff, k5 = pk.z >> 16;
        int k6 = pk.w & 0xffff, k7 = pk.w >> 16;
        ulonglong2 v0 = R2[(size_t)k0 * 64 + lane];
        ulonglong2 v1 = R2[(size_t)k1 * 64 + lane];
        ulonglong2 v2 = R2[(size_t)k2 * 64 + lane];
        ulonglong2 v3 = R2[(size_t)k3 * 64 + lane];
        ulonglong2 v4 = R2[(size_t)k4 * 64 + lane];
        ulonglong2 v5 = R2[(size_t)k5 * 64 + lane];
        ulonglong2 v6 = R2[(size_t)k6 * 64 + lane];
        ulonglong2 v7 = R2[(size_t)k7 * 64 + lane];
        acc0 |= ((v0.x | v1.x) | (v2.x | v3.x)) | ((v4.x | v5.x) | (v6.x | v7.x));
        acc1 |= ((v0.y | v1.y) | (v2.y | v3.y)) | ((v4.y | v5.y) | (v6.y | v7.y));
    }
    T[wave][lane * 2]     = acc0;
    T[wave][lane * 2 + 1] = acc1;
    // no __syncthreads: T is consumed only by this wave

    // --- phase 2: gather bits at selected columns (pi-encoded), row sum, write
    const uint64_t* Tw = T[wave];
    uint64_t bits = 0;
    #pragma unroll
    for (int it = 0; it < 16; ++it) {
        int4 j4 = *(const int4*)&idx_s[it * 256 + lane * 4];
        uint64_t b0 = (Tw[((j4.x >> 8) << 2) | (j4.x & 3)] >> ((j4.x >> 2) & 63)) & 1ull;
        uint64_t b1 = (Tw[((j4.y >> 8) << 2) | (j4.y & 3)] >> ((j4.y >> 2) & 63)) & 1ull;
        uint64_t b2 = (Tw[((j4.z >> 8) << 2) | (j4.z & 3)] >> ((j4.z >> 2) & 63)) & 1ull;
        uint64_t b3 = (Tw[((j4.w >> 8) << 2) | (j4.w & 3)] >> ((j4.w >> 2) & 63)) & 1ull;
        bits |= (b0 << (it * 4)) | (b1 << (it * 4 + 1))
              | (b2 << (it * 4 + 2)) | (b3 << (it * 4 + 3));
    }
    int cnt = __popcll(bits);
    #pragma unroll
    for (int off = 32; off >= 1; off >>= 1) cnt += __shfl_xor(cnt, off);
    float recip = 1.0f / (float)cnt;  // bit * recip == exact 1/rowsum

    float4* dst = (float4*)(out_g + (size_t)r * KSEL);
    #pragma unroll
    for (int it = 0; it < 16; ++it) {
        float4 v;
        v.x = ((bits >> (it * 4 + 0)) & 1ull) ? recip : 0.0f;
        v.y = ((bits >> (it * 4 + 1)) & 1ull) ? recip : 0.0f;
        v.z = ((bits >> (it * 4 + 2)) & 1ull) ? recip : 0.0f;
        v.w = ((bits >> (it * 4 + 3)) & 1ull) ? recip : 0.0f;
        dst[it * 64 + lane] = v;
    }
}

extern "C" void kernel_launch(void* const* d_in, const int* in_sizes, int n_in,
                              void* d_out, int out_size, void* d_ws, size_t ws_size,
                              hipStream_t stream) {
    const float* g = (const float*)d_in[0];
    const float* h = (const float*)d_in[1];
    const float* W = (const float*)d_in[2];
    const float* b = (const float*)d_in[3];

    float* out_g   = (float*)d_out;                                   // K*K
    float* out_h   = out_g + (size_t)KSEL * KSEL;                     // K*D
    float* out_idx = out_h + (size_t)KSEL * DD;                       // K

    char* ws = (char*)d_ws;
    double*   w64    = (double*)ws;                      // 64 KB
    float*    val    = (float*)(ws + 65536);             // 32 KB
    int*      idx_i  = (int*)(ws + 98304);               // 16 KB
    uint64_t* R      = (uint64_t*)(ws + 131072);         // 8 MB

    k_scores<<<NN / 4, 256, 0, stream>>>(h, W, b, w64, val);
    k_pack<<<NN / 4, 256, 0, stream>>>(g, R);
    k_topk<<<NN / 16, 1024, 0, stream>>>(w64, idx_i, out_idx);
    k_newh<<<KSEL, 128, 0, stream>>>(h, val, idx_i, out_h);
    k_newg<<<KSEL / 4, 256, 0, stream>>>(R, idx_i, out_g);
}

// Round 7
// 110.959 us; speedup vs baseline: 6.5418x; 1.1216x over previous
//
#include <hip/hip_runtime.h>
#include <stdint.h>
#include <math.h>

#define NN 8192
#define DD 512
#define KSEL 4096
#define NW 128  // 64-bit words per row bitset (8192 bits)

typedef float f32x4 __attribute__((ext_vector_type(4)));  // NT-builtin-compatible

// Bit permutation pi (internal to R/T bitsets):
//   column c = g*256 + l*4 + e  (g=c>>8, l=(c>>2)&63, e=c&3)
//   stored at word g*4 + e, bit l.

// ------------- Kernel 1: fused pack (blocks 0..2047) + scores (2048..4095) --
__global__ __launch_bounds__(256) void k_pack_scores(const float* __restrict__ g,
                                                     const float* __restrict__ h,
                                                     const float* __restrict__ W,
                                                     const float* __restrict__ b,
                                                     uint64_t* __restrict__ R,
                                                     double* __restrict__ w64,
                                                     float* __restrict__ val) {
    int wave = threadIdx.x >> 6;
    int lane = threadIdx.x & 63;
    if (blockIdx.x < 2048) {
        // ---- pack g rows into pi-permuted bitsets
        int row = blockIdx.x * 4 + wave;
        const f32x4* gr = (const f32x4*)(g + (size_t)row * NN);
        uint64_t* Rr = R + (size_t)row * NW;
        #pragma unroll 4
        for (int gi = 0; gi < 32; ++gi) {
            f32x4 v = __builtin_nontemporal_load(&gr[gi * 64 + lane]);
            int n = (v.x != 0.0f) | ((v.y != 0.0f) << 1)
                  | ((v.z != 0.0f) << 2) | ((v.w != 0.0f) << 3);
            uint64_t b0 = __ballot(n & 1);
            uint64_t b1 = __ballot(n & 2);
            uint64_t b2 = __ballot(n & 4);
            uint64_t b3 = __ballot(n & 8);
            if (lane == 0) {
                Rr[gi * 4 + 0] = b0;
                Rr[gi * 4 + 1] = b1;
                Rr[gi * 4 + 2] = b2;
                Rr[gi * 4 + 3] = b3;
            }
        }
    } else {
        // ---- scores: w64 = h @ W + b (f64), val = sigmoid(w64)
        int row = (blockIdx.x - 2048) * 4 + wave;
        const float4* h4 = (const float4*)(h + (size_t)row * DD);
        const float4* w4 = (const float4*)W;
        float4 a0 = h4[lane * 2], a1 = h4[lane * 2 + 1];
        float4 b0 = w4[lane * 2], b1 = w4[lane * 2 + 1];
        double p = (double)a0.x * (double)b0.x + (double)a0.y * (double)b0.y
                 + (double)a0.z * (double)b0.z + (double)a0.w * (double)b0.w
                 + (double)a1.x * (double)b1.x + (double)a1.y * (double)b1.y
                 + (double)a1.z * (double)b1.z + (double)a1.w * (double)b1.w;
        #pragma unroll
        for (int off = 32; off >= 1; off >>= 1) p += __shfl_xor(p, off);
        if (lane == 0) {
            double wgt = p + (double)b[0];
            w64[row] = wgt;
            val[row] = (float)(1.0 / (1.0 + exp(-wgt)));
        }
    }
}

// ------------- Kernel 2: top-K rank on f64 keys + fused new_h row copy ------
__global__ __launch_bounds__(1024) void k_topk(const double* __restrict__ w64,
                                               const float* __restrict__ val,
                                               const float* __restrict__ h,
                                               int* __restrict__ idx_i,
                                               float* __restrict__ idx_f,
                                               float* __restrict__ out_h) {
    __shared__ double s[NN];  // 64 KB
    for (int t = threadIdx.x; t < NN; t += 1024) s[t] = w64[t];
    __syncthreads();

    int wave = threadIdx.x >> 6;          // 0..15
    int lane = threadIdx.x & 63;
    int i = blockIdx.x * 16 + wave;
    double wi = s[i];
    int rank = 0;
    #pragma unroll 4
    for (int j = lane; j < NN; j += 64) {
        double wj = s[j];
        rank += (wj > wi) || (wj == wi && j < i);
    }
    #pragma unroll
    for (int off = 32; off >= 1; off >>= 1) rank += __shfl_xor(rank, off);

    if (rank < KSEL) {
        // all 64 lanes copy/scale the selected h row (fused new_h)
        float v = val[i];
        const f32x4* src = (const f32x4*)(h + (size_t)i * DD);
        f32x4* dst = (f32x4*)(out_h + (size_t)rank * DD);
        #pragma unroll
        for (int t = 0; t < 2; ++t) {
            f32x4 x = src[lane + t * 64];
            x *= v;
            __builtin_nontemporal_store(x, &dst[lane + t * 64]);
        }
        if (lane == 0) {
            idx_i[rank] = i;
            idx_f[rank] = (float)i;
        }
    }
}

// ------------- Kernel 3: new_g rows via bitset OR; 2 waves per output row ---
__global__ __launch_bounds__(256) void k_newg(const uint64_t* __restrict__ R,
                                              const int* __restrict__ idx_i,
                                              float* __restrict__ out_g) {
    __shared__ uint16_t idx_s[KSEL];                   // 8 KB
    __shared__ uint64_t T[4][NW];                      // 4 KB (per-wave partial)
    __shared__ __align__(16) uint16_t nbr[2][536];     // ~2.1 KB per-row lists
    __shared__ int cpart[4];
    for (int t = threadIdx.x; t < KSEL; t += 256) idx_s[t] = (uint16_t)idx_i[t];
    __syncthreads();

    int wave = threadIdx.x >> 6;
    int lane = threadIdx.x & 63;
    int wid  = wave >> 1;        // which of the block's 2 rows
    int half = wave & 1;         // which half-worker for that row
    int r = blockIdx.x * 2 + wid;
    int i = (int)idx_s[r];

    // --- neighbor-list extraction (duplicated by both waves of the row;
    //     identical values -> benign concurrent LDS writes, no extra sync)
    const ulonglong2* R2 = (const ulonglong2*)R;       // 64 per row
    ulonglong2 own = R2[(size_t)i * 64 + lane];
    uint64_t m0 = own.x, m1 = own.y;
    int mycnt = __popcll(m0) + __popcll(m1);
    int incl = mycnt;
    #pragma unroll
    for (int d = 1; d < 64; d <<= 1) {
        int v = __shfl_up(incl, d);
        if (lane >= d) incl += v;
    }
    int pos = incl - mycnt;                 // exclusive prefix
    int total = __shfl(incl, 63);
    int w0 = lane * 2, w1 = lane * 2 + 1;
    while (m0) {
        int l = __builtin_ctzll(m0); m0 &= m0 - 1;
        nbr[wid][pos++] = (uint16_t)(((w0 >> 2) << 8) + (l << 2) + (w0 & 3));
    }
    while (m1) {
        int l = __builtin_ctzll(m1); m1 &= m1 - 1;
        nbr[wid][pos++] = (uint16_t)(((w1 >> 2) << 8) + (l << 2) + (w1 & 3));
    }
    int totalPad = (total + 7) & ~7;        // pad with entry 0 (OR idempotent)
    if (lane < totalPad - total) nbr[wid][total + lane] = nbr[wid][0];

    // --- phase 1: OR neighbor bitsets; the 2 waves take alternate 8-groups
    uint64_t acc0 = 0, acc1 = 0;
    const uint16_t* nb = nbr[wid];
    for (int n = half * 8; n < totalPad; n += 16) {
        uint4 pk = *(const uint4*)&nb[n];
        int k0 = pk.x & 0xffff, k1 = pk.x >> 16;
        int k2 = pk.y & 0xffff, k3 = pk.y >> 16;
        int k4 = pk.z & 0xffff, k5 = pk.z >> 16;
        int k6 = pk.w & 0xffff, k7 = pk.w >> 16;
        ulonglong2 v0 = R2[(size_t)k0 * 64 + lane];
        ulonglong2 v1 = R2[(size_t)k1 * 64 + lane];
        ulonglong2 v2 = R2[(size_t)k2 * 64 + lane];
        ulonglong2 v3 = R2[(size_t)k3 * 64 + lane];
        ulonglong2 v4 = R2[(size_t)k4 * 64 + lane];
        ulonglong2 v5 = R2[(size_t)k5 * 64 + lane];
        ulonglong2 v6 = R2[(size_t)k6 * 64 + lane];
        ulonglong2 v7 = R2[(size_t)k7 * 64 + lane];
        acc0 |= ((v0.x | v1.x) | (v2.x | v3.x)) | ((v4.x | v5.x) | (v6.x | v7.x));
        acc1 |= ((v0.y | v1.y) | (v2.y | v3.y)) | ((v4.y | v5.y) | (v6.y | v7.y));
    }
    T[wave][lane * 2]     = acc0;
    T[wave][lane * 2 + 1] = acc1;
    __syncthreads();

    // --- phase 2: this wave handles 8 of the row's 16 column-iterations
    const uint64_t* Ta = T[2 * wid];
    const uint64_t* Tb = T[2 * wid + 1];
    uint32_t bits = 0;
    #pragma unroll
    for (int it = 0; it < 8; ++it) {
        ushort4 j4 = *(const ushort4*)&idx_s[(half * 8 + it) * 256 + lane * 4];
        int wx = ((j4.x >> 8) << 2) | (j4.x & 3);
        int wy = ((j4.y >> 8) << 2) | (j4.y & 3);
        int wz = ((j4.z >> 8) << 2) | (j4.z & 3);
        int ww = ((j4.w >> 8) << 2) | (j4.w & 3);
        uint32_t b0 = (uint32_t)(((Ta[wx] | Tb[wx]) >> ((j4.x >> 2) & 63)) & 1ull);
        uint32_t b1 = (uint32_t)(((Ta[wy] | Tb[wy]) >> ((j4.y >> 2) & 63)) & 1ull);
        uint32_t b2 = (uint32_t)(((Ta[wz] | Tb[wz]) >> ((j4.z >> 2) & 63)) & 1ull);
        uint32_t b3 = (uint32_t)(((Ta[ww] | Tb[ww]) >> ((j4.w >> 2) & 63)) & 1ull);
        bits |= (b0 << (it * 4)) | (b1 << (it * 4 + 1))
              | (b2 << (it * 4 + 2)) | (b3 << (it * 4 + 3));
    }
    int cnt = __popc(bits);
    #pragma unroll
    for (int off = 32; off >= 1; off >>= 1) cnt += __shfl_xor(cnt, off);
    if (lane == 0) cpart[wave] = cnt;
    __syncthreads();
    int tot = cpart[2 * wid] + cpart[2 * wid + 1];
    float recip = 1.0f / (float)tot;  // bit * recip == exact 1/rowsum

    f32x4* dst = (f32x4*)(out_g + (size_t)r * KSEL);
    #pragma unroll
    for (int it = 0; it < 8; ++it) {
        f32x4 v;
        v.x = ((bits >> (it * 4 + 0)) & 1u) ? recip : 0.0f;
        v.y = ((bits >> (it * 4 + 1)) & 1u) ? recip : 0.0f;
        v.z = ((bits >> (it * 4 + 2)) & 1u) ? recip : 0.0f;
        v.w = ((bits >> (it * 4 + 3)) & 1u) ? recip : 0.0f;
        __builtin_nontemporal_store(v, &dst[(half * 8 + it) * 64 + lane]);
    }
}

extern "C" void kernel_launch(void* const* d_in, const int* in_sizes, int n_in,
                              void* d_out, int out_size, void* d_ws, size_t ws_size,
                              hipStream_t stream) {
    const float* g = (const float*)d_in[0];
    const float* h = (const float*)d_in[1];
    const float* W = (const float*)d_in[2];
    const float* b = (const float*)d_in[3];

    float* out_g   = (float*)d_out;                                   // K*K
    float* out_h   = out_g + (size_t)KSEL * KSEL;                     // K*D
    float* out_idx = out_h + (size_t)KSEL * DD;                       // K

    char* ws = (char*)d_ws;
    double*   w64    = (double*)ws;                      // 64 KB
    float*    val    = (float*)(ws + 65536);             // 32 KB
    int*      idx_i  = (int*)(ws + 98304);               // 16 KB
    uint64_t* R      = (uint64_t*)(ws + 131072);         // 8 MB

    k_pack_scores<<<4096, 256, 0, stream>>>(g, h, W, b, R, w64, val);
    k_topk<<<NN / 16, 1024, 0, stream>>>(w64, val, h, idx_i, out_idx, out_h);
    k_newg<<<KSEL / 2, 256, 0, stream>>>(R, idx_i, out_g);
}

// Round 8
// 103.980 us; speedup vs baseline: 6.9809x; 1.0671x over previous
//
#include <hip/hip_runtime.h>
#include <stdint.h>
#include <math.h>

#define NN 8192
#define DD 512
#define KSEL 4096
#define NW 128  // 64-bit words per full row bitset (8192 bits)

typedef float f32x4 __attribute__((ext_vector_type(4)));

// pi-8192 (full bitsets R): column j = g*256 + l*4 + e (g=j>>8,l=(j>>2)&63,e=j&3)
//   -> word g*4+e (128 words), bit l.
// pi-4096 (selected bitsets Rsel): position c = it*256 + l*4 + e
//   -> word it*4+e (64 words), bit l.

// ------------- Kernel 1: fused pack (blocks 0..2047) + scores (2048..4095) --
__global__ __launch_bounds__(256) void k_pack_scores(const float* __restrict__ g,
                                                     const float* __restrict__ h,
                                                     const float* __restrict__ W,
                                                     const float* __restrict__ b,
                                                     uint64_t* __restrict__ R,
                                                     double* __restrict__ w64,
                                                     float* __restrict__ val) {
    int wave = threadIdx.x >> 6;
    int lane = threadIdx.x & 63;
    if (blockIdx.x < 2048) {
        int row = blockIdx.x * 4 + wave;
        const f32x4* gr = (const f32x4*)(g + (size_t)row * NN);
        uint64_t* Rr = R + (size_t)row * NW;
        #pragma unroll 4
        for (int gi = 0; gi < 32; ++gi) {
            f32x4 v = __builtin_nontemporal_load(&gr[gi * 64 + lane]);
            int n = (v.x != 0.0f) | ((v.y != 0.0f) << 1)
                  | ((v.z != 0.0f) << 2) | ((v.w != 0.0f) << 3);
            uint64_t b0 = __ballot(n & 1);
            uint64_t b1 = __ballot(n & 2);
            uint64_t b2 = __ballot(n & 4);
            uint64_t b3 = __ballot(n & 8);
            if (lane == 0) {
                Rr[gi * 4 + 0] = b0;
                Rr[gi * 4 + 1] = b1;
                Rr[gi * 4 + 2] = b2;
                Rr[gi * 4 + 3] = b3;
            }
        }
    } else {
        int row = (blockIdx.x - 2048) * 4 + wave;
        const float4* h4 = (const float4*)(h + (size_t)row * DD);
        const float4* w4 = (const float4*)W;
        float4 a0 = h4[lane * 2], a1 = h4[lane * 2 + 1];
        float4 b0 = w4[lane * 2], b1 = w4[lane * 2 + 1];
        double p = (double)a0.x * (double)b0.x + (double)a0.y * (double)b0.y
                 + (double)a0.z * (double)b0.z + (double)a0.w * (double)b0.w
                 + (double)a1.x * (double)b1.x + (double)a1.y * (double)b1.y
                 + (double)a1.z * (double)b1.z + (double)a1.w * (double)b1.w;
        #pragma unroll
        for (int off = 32; off >= 1; off >>= 1) p += __shfl_xor(p, off);
        if (lane == 0) {
            double wgt = p + (double)b[0];
            w64[row] = wgt;
            val[row] = (float)(1.0 / (1.0 + exp(-wgt)));
        }
    }
}

// ------------- Kernel 2: top-K rank on f64 keys + fused new_h row copy ------
__global__ __launch_bounds__(1024) void k_topk(const double* __restrict__ w64,
                                               const float* __restrict__ val,
                                               const float* __restrict__ h,
                                               int* __restrict__ idx_i,
                                               float* __restrict__ idx_f,
                                               float* __restrict__ out_h) {
    __shared__ double s[NN];  // 64 KB
    for (int t = threadIdx.x; t < NN; t += 1024) s[t] = w64[t];
    __syncthreads();

    int wave = threadIdx.x >> 6;
    int lane = threadIdx.x & 63;
    int i = blockIdx.x * 16 + wave;
    double wi = s[i];
    int rank = 0;
    #pragma unroll 4
    for (int j = lane; j < NN; j += 64) {
        double wj = s[j];
        rank += (wj > wi) || (wj == wi && j < i);
    }
    #pragma unroll
    for (int off = 32; off >= 1; off >>= 1) rank += __shfl_xor(rank, off);

    if (rank < KSEL) {
        float v = val[i];
        const f32x4* src = (const f32x4*)(h + (size_t)i * DD);
        f32x4* dst = (f32x4*)(out_h + (size_t)rank * DD);
        #pragma unroll
        for (int t = 0; t < 2; ++t) {
            f32x4 x = src[lane + t * 64];
            x *= v;
            __builtin_nontemporal_store(x, &dst[lane + t * 64]);
        }
        if (lane == 0) {
            idx_i[rank] = i;
            idx_f[rank] = (float)i;
        }
    }
}

// ------------- Kernel 3: Rsel[k] = selected-column bits of R[k] (pi-4096) ---
__global__ __launch_bounds__(512) void k_sel(const uint64_t* __restrict__ R,
                                             const int* __restrict__ idx_i,
                                             uint64_t* __restrict__ Rsel) {
    __shared__ uint16_t idx_s[KSEL];   // 8 KB
    __shared__ uint64_t rb[8][NW];     // 8 KB full bitsets of this block's rows
    for (int t = threadIdx.x; t < KSEL; t += 512) idx_s[t] = (uint16_t)idx_i[t];

    int wave = threadIdx.x >> 6;
    int lane = threadIdx.x & 63;
    int row  = blockIdx.x * 8 + wave;
    const ulonglong2* R2 = (const ulonglong2*)R;
    ulonglong2 own = R2[(size_t)row * 64 + lane];
    rb[wave][2 * lane]     = own.x;
    rb[wave][2 * lane + 1] = own.y;
    __syncthreads();

    const uint64_t* rw = rb[wave];
    uint64_t v = 0;
    #pragma unroll
    for (int it = 0; it < 16; ++it) {
        ushort4 j4 = *(const ushort4*)&idx_s[it * 256 + lane * 4];
        int wx = ((j4.x >> 8) << 2) | (j4.x & 3);
        int wy = ((j4.y >> 8) << 2) | (j4.y & 3);
        int wz = ((j4.z >> 8) << 2) | (j4.z & 3);
        int ww = ((j4.w >> 8) << 2) | (j4.w & 3);
        int n = (int)((rw[wx] >> ((j4.x >> 2) & 63)) & 1ull)
              | ((int)((rw[wy] >> ((j4.y >> 2) & 63)) & 1ull) << 1)
              | ((int)((rw[wz] >> ((j4.z >> 2) & 63)) & 1ull) << 2)
              | ((int)((rw[ww] >> ((j4.w >> 2) & 63)) & 1ull) << 3);
        uint64_t b0 = __ballot(n & 1);
        uint64_t b1 = __ballot(n & 2);
        uint64_t b2 = __ballot(n & 4);
        uint64_t b3 = __ballot(n & 8);
        if ((lane >> 2) == it) {
            int e = lane & 3;
            v = (e == 0) ? b0 : (e == 1) ? b1 : (e == 2) ? b2 : b3;
        }
    }
    Rsel[(size_t)row * 64 + lane] = v;   // coalesced 512B per wave
}

// ------------- Kernel 4: new_g row r = OR of Rsel over nbr(idx[r]) ----------
__global__ __launch_bounds__(256) void k_newg(const uint64_t* __restrict__ R,
                                              const uint64_t* __restrict__ Rsel,
                                              const int* __restrict__ idx_i,
                                              float* __restrict__ out_g) {
    __shared__ __align__(16) uint16_t nbr[544];  // padded neighbor list
    __shared__ uint64_t T[4][64];                // per-wave partial ORs
    __shared__ uint64_t C[64];                   // combined row bitset

    int wave = threadIdx.x >> 6;
    int lane = threadIdx.x & 63;
    int r = blockIdx.x;
    int i = idx_i[r];

    // --- neighbor-list extraction (duplicated by all 4 waves; identical
    //     values -> benign concurrent LDS writes; own writes self-consistent)
    const ulonglong2* R2 = (const ulonglong2*)R;
    ulonglong2 own = R2[(size_t)i * 64 + lane];
    uint64_t m0 = own.x, m1 = own.y;
    int mycnt = __popcll(m0) + __popcll(m1);
    int incl = mycnt;
    #pragma unroll
    for (int d = 1; d < 64; d <<= 1) {
        int t = __shfl_up(incl, d);
        if (lane >= d) incl += t;
    }
    int pos = incl - mycnt;
    int total = __shfl(incl, 63);
    int w0 = lane * 2, w1 = lane * 2 + 1;
    while (m0) {
        int l = __builtin_ctzll(m0); m0 &= m0 - 1;
        nbr[pos++] = (uint16_t)(((w0 >> 2) << 8) + (l << 2) + (w0 & 3));
    }
    while (m1) {
        int l = __builtin_ctzll(m1); m1 &= m1 - 1;
        nbr[pos++] = (uint16_t)(((w1 >> 2) << 8) + (l << 2) + (w1 & 3));
    }
    int totalPad = (total + 7) & ~7;   // pad with entry 0 (OR idempotent)
    if (lane < totalPad - total) nbr[total + lane] = nbr[0];

    // --- phase 1: OR Rsel rows; each wave takes every 4th batch of 8
    uint64_t acc = 0;
    for (int n = wave * 8; n < totalPad; n += 32) {
        uint4 pk = *(const uint4*)&nbr[n];
        int k0 = pk.x & 0xffff, k1 = pk.x >> 16;
        int k2 = pk.y & 0xffff, k3 = pk.y >> 16;
        int k4 = pk.z & 0xffff, k5 = pk.z >> 16;
        int k6 = pk.w & 0xffff, k7 = pk.w >> 16;
        uint64_t v0 = Rsel[(size_t)k0 * 64 + lane];
        uint64_t v1 = Rsel[(size_t)k1 * 64 + lane];
        uint64_t v2 = Rsel[(size_t)k2 * 64 + lane];
        uint64_t v3 = Rsel[(size_t)k3 * 64 + lane];
        uint64_t v4 = Rsel[(size_t)k4 * 64 + lane];
        uint64_t v5 = Rsel[(size_t)k5 * 64 + lane];
        uint64_t v6 = Rsel[(size_t)k6 * 64 + lane];
        uint64_t v7 = Rsel[(size_t)k7 * 64 + lane];
        acc |= ((v0 | v1) | (v2 | v3)) | ((v4 | v5) | (v6 | v7));
    }
    T[wave][lane] = acc;
    __syncthreads();

    uint64_t comb = T[0][lane] | T[1][lane] | T[2][lane] | T[3][lane];
    C[lane] = comb;   // every wave writes all 64 words (identical values)
    int cnt = __popcll(comb);
    #pragma unroll
    for (int off = 32; off >= 1; off >>= 1) cnt += __shfl_xor(cnt, off);
    float recip = 1.0f / (float)cnt;   // bit * recip == exact 1/rowsum

    // --- phase 2: wave writes its 4 of the 16 column-iterations
    f32x4* dst = (f32x4*)(out_g + (size_t)r * KSEL);
    #pragma unroll
    for (int s = 0; s < 4; ++s) {
        int it = wave * 4 + s;
        uint64_t wA = C[it * 4 + 0], wB = C[it * 4 + 1];
        uint64_t wC = C[it * 4 + 2], wD = C[it * 4 + 3];
        f32x4 v;
        v.x = ((wA >> lane) & 1ull) ? recip : 0.0f;
        v.y = ((wB >> lane) & 1ull) ? recip : 0.0f;
        v.z = ((wC >> lane) & 1ull) ? recip : 0.0f;
        v.w = ((wD >> lane) & 1ull) ? recip : 0.0f;
        __builtin_nontemporal_store(v, &dst[it * 64 + lane]);
    }
}

extern "C" void kernel_launch(void* const* d_in, const int* in_sizes, int n_in,
                              void* d_out, int out_size, void* d_ws, size_t ws_size,
                              hipStream_t stream) {
    const float* g = (const float*)d_in[0];
    const float* h = (const float*)d_in[1];
    const float* W = (const float*)d_in[2];
    const float* b = (const float*)d_in[3];

    float* out_g   = (float*)d_out;                                   // K*K
    float* out_h   = out_g + (size_t)KSEL * KSEL;                     // K*D
    float* out_idx = out_h + (size_t)KSEL * DD;                       // K

    char* ws = (char*)d_ws;
    double*   w64    = (double*)ws;                          // 64 KB
    float*    val    = (float*)(ws + 65536);                 // 32 KB
    int*      idx_i  = (int*)(ws + 98304);                   // 16 KB
    uint64_t* R      = (uint64_t*)(ws + 131072);             // 8 MB
    uint64_t* Rsel   = (uint64_t*)(ws + 131072 + 8388608);   // 4 MB

    k_pack_scores<<<4096, 256, 0, stream>>>(g, h, W, b, R, w64, val);
    k_topk<<<NN / 16, 1024, 0, stream>>>(w64, val, h, idx_i, out_idx, out_h);
    k_sel<<<NN / 8, 512, 0, stream>>>(R, idx_i, Rsel);
    k_newg<<<KSEL, 256, 0, stream>>>(R, Rsel, idx_i, out_g);
}